// Round 1
// 5506.511 us; speedup vs baseline: 1.8823x; 1.8823x over previous
//
#include <hip/hip_runtime.h>

#define B_ 256
#define T_ 512
#define V_ 128
#define E_ 128
#define H_ 256
#define FH 1024

#define GROUPS 32
#define RPG 8      // batch rows per group
#define CWG 16     // column-WGs per group
#define NWG (GROUPS*CWG)

#define HTG (H_*RPG)          // 2048 floats: one group's h, one buffer
#define GST (GROUPS*HTG)      // one buffer stride

typedef float f4 __attribute__((ext_vector_type(4)));

// ---- workspace layout (float offsets) ----
#define OFF_HT0  0                              // h0 [2buf][grp][256k][8rows]
#define OFF_HT1  (OFF_HT0 + 2*GST)              // h1 same layout
#define OFF_BAR  (OFF_HT1 + 2*GST)              // 32 groups * 128 uints (512B stride)
#define OFF_TP   (OFF_BAR + 4096)               // TokProj [V][1024] packed
#define OFF_CP   (OFF_TP + V_*FH)               // ClusProj [B][1024] packed (+b0)
#define OFF_WP0  (OFF_CP + B_*FH)               // W0h x4-packed [16c][64kb][64lane][4j]
#define OFF_WP1  (OFF_WP0 + CWG*64*64*4)        // W1  x4-packed [16c][128kb][64lane][4j]
#define OFF_DWT  (OFF_WP1 + CWG*128*64*4)       // decoderW^T [128v][256k]
#define OFF_B1   (OFF_DWT + V_*H_)              // b1 packed [1024]

// packed column order: local col = u*4+g  ->  global z-col G = g*256 + c*16 + u
__device__ __forceinline__ int gcol(int c, int col) {
  int u = col >> 2, g = col & 3;
  return g*256 + c*16 + u;
}

__device__ __forceinline__ float sigm(float x){ return 1.f/(1.f+__expf(-x)); }
__device__ __forceinline__ float tanh_(float x){ return 1.f - 2.f/(1.f+__expf(2.f*x)); }

// ============ prep kernels ============

__global__ void prep_pack(const float* __restrict__ W0, const float* __restrict__ W1,
                          const float* __restrict__ dW, const float* __restrict__ b1,
                          float* __restrict__ ws) {
  float* wp0 = ws + OFF_WP0; float* wp1 = ws + OFF_WP1;
  float* dwT = ws + OFF_DWT; float* b1p = ws + OFF_B1;
  const int N0 = CWG*64*64*4;     // 262144
  const int N1 = CWG*128*64*4;    // 524288
  const int N2 = V_*H_;           // 32768
  const int N3 = FH;              // 1024
  const int total = N0+N1+N2+N3;
  for (int i = blockIdx.x*blockDim.x + threadIdx.x; i < total; i += gridDim.x*blockDim.x) {
    if (i < N0) {
      int cc = i >> 14; int rem = i & 16383;
      int kb = rem >> 8; int ln = (rem >> 2) & 63; int j = i & 3;
      int k = kb*4 + j;
      wp0[i] = W0[(E_+H_+k)*FH + gcol(cc, ln)];          // W0 h0-rows
    } else if (i < N0+N1) {
      int idx = i - N0;
      int cc = idx >> 15; int rem = idx & 32767;
      int kb = rem >> 8; int ln = (rem >> 2) & 63; int j = idx & 3;
      int k2 = kb*4 + j;                                  // 0..255 h0n, 256..511 h1
      wp1[idx] = W1[k2*FH + gcol(cc, ln)];
    } else if (i < N0+N1+N2) {
      int l = i - N0 - N1;
      int v = l >> 8, k = l & 255;
      dwT[l] = dW[k*V_ + v];
    } else {
      int cc2 = i - N0 - N1 - N2;
      b1p[cc2] = b1[gcol(cc2>>6, cc2&63)];
    }
  }
}

__global__ void prep_tok(const float* __restrict__ cemb, const float* __restrict__ W0,
                         float* __restrict__ ws) {
  __shared__ float ce[E_];
  float* TP = ws + OFF_TP;
  int v = blockIdx.x >> 2, q = blockIdx.x & 3;
  int tid = threadIdx.x;
  if (tid < E_) ce[tid] = cemb[v*E_ + tid];
  __syncthreads();
  int ccol = q*256 + tid;
  int G = gcol(ccol>>6, ccol&63);
  float acc = 0.f;
  for (int e = 0; e < E_; ++e) acc = fmaf(ce[e], W0[e*FH + G], acc);
  TP[v*FH + ccol] = acc;
}

__global__ void prep_clus(const int* __restrict__ clus, const float* __restrict__ clemb,
                          const float* __restrict__ W0, const float* __restrict__ b0,
                          float* __restrict__ ws) {
  __shared__ float ce[H_];
  float* CP = ws + OFF_CP;
  int b = blockIdx.x >> 2, q = blockIdx.x & 3;
  int tid = threadIdx.x;
  int cl = clus[b];
  ce[tid] = clemb[(long long)cl*H_ + tid];
  __syncthreads();
  int ccol = q*256 + tid;
  int G = gcol(ccol>>6, ccol&63);
  float acc = b0[G];
  for (int e = 0; e < H_; ++e) acc = fmaf(ce[e], W0[(E_+e)*FH + G], acc);
  CP[b*FH + ccol] = acc;
}

// ============ sync & staging primitives ============

__device__ __forceinline__ void st_coh(float* p, float v) {
  __hip_atomic_store(p, v, __ATOMIC_RELAXED, __HIP_MEMORY_SCOPE_AGENT);
}

// stage one h row (8 floats, 32B) coherently: 4 x u64 agent-scope loads -> LDS
__device__ __forceinline__ void stage_row(const float* g, float* l) {
  const unsigned long long* p = (const unsigned long long*)g;
  unsigned long long d0 = __hip_atomic_load(p+0, __ATOMIC_RELAXED, __HIP_MEMORY_SCOPE_AGENT);
  unsigned long long d1 = __hip_atomic_load(p+1, __ATOMIC_RELAXED, __HIP_MEMORY_SCOPE_AGENT);
  unsigned long long d2 = __hip_atomic_load(p+2, __ATOMIC_RELAXED, __HIP_MEMORY_SCOPE_AGENT);
  unsigned long long d3 = __hip_atomic_load(p+3, __ATOMIC_RELAXED, __HIP_MEMORY_SCOPE_AGENT);
  float2 f0 = __builtin_bit_cast(float2, d0);
  float2 f1 = __builtin_bit_cast(float2, d1);
  float2 f2 = __builtin_bit_cast(float2, d2);
  float2 f3 = __builtin_bit_cast(float2, d3);
  f4 lo = {f0.x, f0.y, f1.x, f1.y};
  f4 hi = {f2.x, f2.y, f3.x, f3.y};
  *(f4*)(l)     = lo;
  *(f4*)(l + 4) = hi;
}

// relaxed flag publish ordered by explicit vmcnt drain — avoids the RELEASE
// path's potential buffer_wbl2 (L2 writeback) on gfx950. All prior h-stores
// are agent-scope (coherence-point) ops; vmcnt(0) guarantees they completed
// at the coherence point before the flag store issues.
__device__ __forceinline__ void flag_set(unsigned* p, unsigned v) {
  asm volatile("s_waitcnt vmcnt(0)" ::: "memory");
  __hip_atomic_store(p, v, __ATOMIC_RELAXED, __HIP_MEMORY_SCOPE_AGENT);
}

// wave-0-only poll of BOTH flag lines (fA via lanes 0-31, fB via lanes 32-63)
__device__ __forceinline__ void spinAB(const unsigned* fA, const unsigned* fB,
                                       int lane, unsigned tgt) {
  const unsigned* p = ((lane < 32) ? fA : fB) + (lane & 15);
  unsigned v = __hip_atomic_load(p, __ATOMIC_RELAXED, __HIP_MEMORY_SCOPE_AGENT);
  while (!__all((int)(v >= tgt))) {
    __builtin_amdgcn_s_sleep(2);
    v = __hip_atomic_load(p, __ATOMIC_RELAXED, __HIP_MEMORY_SCOPE_AGENT);
  }
}

// single-line poll (epilogue, fB only)
__device__ __forceinline__ void spin1(const unsigned* f, int lane, unsigned tgt) {
  const unsigned* p = f + (lane & 15);
  unsigned v = __hip_atomic_load(p, __ATOMIC_RELAXED, __HIP_MEMORY_SCOPE_AGENT);
  while (!__all((int)(v >= tgt))) {
    __builtin_amdgcn_s_sleep(2);
    v = __hip_atomic_load(p, __ATOMIC_RELAXED, __HIP_MEMORY_SCOPE_AGENT);
  }
}

__device__ __forceinline__ void lstm_gate(const f4 z, float& cc, float& hh, const bool upd) {
  float ci = sigm(z.x);
  float cj = tanh_(z.y);
  float cf = sigm(z.z + 1.f);
  float co = sigm(z.w);
  float cn = fmaf(cc, cf, ci*cj);
  float hn = tanh_(cn)*co;
  if (upd) { cc = cn; hh = hn; }
}

// ============ main persistent kernel ============
//
// Merged single-exchange schedule. Invariant at iteration t:
//   buf(t&1) holds { H0(t), H1(t-1) }, flags fA,fB >= t+1 when complete.
// Iteration t:
//   spin(t+1) -> stage both -> fused matvec:
//     a0 = W0h*H0(t)          (-> z0(t+1))
//     a1 = W1lo*H0(t) + W1up*H1(t-1)   (-> z1(t))
//     proj partials from H1(t-1)        (-> out(t-1))
//   reduce: wave0 gates L0 -> publish H0(t+1); wave1 gates L1 -> publish H1(t);
//   wave2 stores out(t-1). One spin, one stage, 3 barriers per step.

__global__ __launch_bounds__(256, 2) void lstm_persist(
    const int* __restrict__ toks, const int* __restrict__ lens,
    const float* __restrict__ decB, float* __restrict__ ws, float* __restrict__ out)
{
  // XCD-colocation swizzle (L2 locality heuristic; correctness is placement-free)
  const int blk  = blockIdx.x;
  const int grp  = ((blk & 7) << 2) | ((blk >> 3) >> 4);  // 0..31
  const int c    = (blk >> 3) & 15;                        // column-WG 0..15
  const int tid  = threadIdx.x;
  const int lane = tid & 63;
  const int wv   = tid >> 6;
  const int cof  = c*64;

  float* ht0 = ws + OFF_HT0;      // [2][GROUPS][HTG]
  float* ht1 = ws + OFF_HT1;
  unsigned* fgrp = (unsigned*)(ws + OFF_BAR) + grp*128;
  unsigned* fA = fgrp;            // 16 slots (one 64B line)
  unsigned* fB = fgrp + 32;       // 16 slots
  const float* TP   = ws + OFF_TP;
  const float* CP   = ws + OFF_CP;
  const float* wp0c = ws + OFF_WP0 + c*(64*64*4);
  const float* wp1c = ws + OFF_WP1 + c*(128*64*4);
  const float* dwT  = ws + OFF_DWT;
  const float* b1p  = ws + OFF_B1;

  __shared__ __align__(16) float h0s[256][8];   // staged H0(t), k-major
  __shared__ __align__(16) float h1s[256][8];   // staged H1(t-1), k-major
  __shared__ float za[4][8][64];                // z0 partials
  __shared__ float zb[4][8][64];                // z1 partials
  __shared__ float ldsW[8][260];                // decoderW slice [v][k], padded
  __shared__ float pred[4][64];                 // projection partials

  // stage decoder weight slice (v = c*8 .. c*8+7)
  for (int i = tid; i < 8*H_; i += 256)
    ldsW[i>>8][i&255] = dwT[(c*8 + (i>>8))*H_ + (i&255)];

  // staging row index (staggered across c to spread first-touch lines)
  const int sk = (tid + (c << 4)) & 255;

  // ---- group max length (all lanes) ----
  int Lg = lens[grp*RPG + (lane & 7)];
  Lg = max(Lg, __shfl_xor(Lg, 1));
  Lg = max(Lg, __shfl_xor(Lg, 2));
  Lg = max(Lg, __shfl_xor(Lg, 4));

  // ---- gate-lane constants (wave0 = layer0, wave1 = layer1) ----
  const int gu = lane & 15, q = lane >> 4;   // unit, row-pair selector
  const int rowA = grp*RPG + q, rowB = grp*RPG + q + 4;
  const int lenA = lens[rowA], lenB = lens[rowB];
  const int* tokApt = toks + rowA*T_;
  const int* tokBpt = toks + rowB*T_;
  const f4 cpA = *(const f4*)(CP + rowA*FH + cof + gu*4);
  const f4 cpB = *(const f4*)(CP + rowB*FH + cof + gu*4);
  const f4 b1v = *(const f4*)(b1p + cof + gu*4);
  const int puboff = grp*HTG + (c*16 + gu)*8;
  float c0A = 0.f, h0A = 0.f, c0B = 0.f, h0B = 0.f;   // wave0 L0 state
  float c1A = 0.f, h1A = 0.f, c1B = 0.f, h1B = 0.f;   // wave1 L1 state

  // ---- projection constants ----
  const int pm = lane >> 3, pv = lane & 7;
  const int plen = lens[grp*RPG + pm];
  const float decb = decB[c*8 + pv];
  float* outp = out + (size_t)(grp*RPG + pm)*T_*V_ + c*8 + pv;

  float a0[8], a1[8];

  __syncthreads();   // ldsW staged

  // ---- prologue: H0(0) from TP+CP (no h term); H1(-1)=0 via pre-zeroed ws ----
  if (wv == 0) {
    int tokA = tokApt[0], tokB = tokBpt[0];
    f4 zA = *(const f4*)(TP + tokA*FH + cof + gu*4) + cpA;
    f4 zB = *(const f4*)(TP + tokB*FH + cof + gu*4) + cpB;
    lstm_gate(zA, c0A, h0A, 0 < lenA);
    lstm_gate(zB, c0B, h0B, 0 < lenB);
    float* pb = ht0 + puboff;                 // buf0
    st_coh(pb + q,     h0A);
    st_coh(pb + q + 4, h0B);
    if (lane == 0) flag_set(fA + c, 1u);
  } else if (wv == 1) {
    if (lane == 0) flag_set(fB + c, 1u);      // h1 buf0 pre-zeroed by memset
  }

  for (int t = 0; t < Lg; ++t) {
    const int buf = t & 1;

    // ---- single wait per step: {H0(t), H1(t-1)} both ready ----
    if (wv == 0) spinAB(fA, fB, lane, (unsigned)(t + 1));
    __syncthreads();                                   // (1)
    __atomic_signal_fence(__ATOMIC_SEQ_CST);

    // TP prefetch for next-step z0 (off the reduce critical path)
    f4 tpA = {0.f,0.f,0.f,0.f}, tpB = {0.f,0.f,0.f,0.f};
    if (wv == 0 && t + 1 < Lg) {
      tpA = *(const f4*)(TP + tokApt[t+1]*FH + cof + gu*4);
      tpB = *(const f4*)(TP + tokBpt[t+1]*FH + cof + gu*4);
    }

    // ---- stage H0(t) and H1(t-1) -> LDS (fused, one barrier) ----
    stage_row(ht0 + buf*GST + grp*HTG + sk*8, &h0s[sk][0]);
    stage_row(ht1 + buf*GST + grp*HTG + sk*8, &h1s[sk][0]);
    __syncthreads();                                   // (2)

    // ---- fused matvec: a0 = W0h*h0; a1 = W1lo*h0 + W1up*h1 ----
    #pragma unroll
    for (int r = 0; r < 8; ++r) { a0[r] = 0.f; a1[r] = 0.f; }
    #pragma unroll 2
    for (int b = 0; b < 16; ++b) {
      const int kb = wv*16 + b;
      const f4 w0  = *(const f4*)(wp0c + kb*256 + lane*4);
      const f4 wlo = *(const f4*)(wp1c + kb*256 + lane*4);
      const f4 wup = *(const f4*)(wp1c + (64 + kb)*256 + lane*4);
      const float* w0a  = (const float*)&w0;
      const float* wloa = (const float*)&wlo;
      const float* wupa = (const float*)&wup;
      #pragma unroll
      for (int j = 0; j < 4; ++j) {
        const int k = kb*4 + j;
        const f4 h0a = *(const f4*)&h0s[k][0];
        const f4 h0b = *(const f4*)&h0s[k][4];
        const f4 h1a = *(const f4*)&h1s[k][0];
        const f4 h1b = *(const f4*)&h1s[k][4];
        const float w0j = w0a[j], wlj = wloa[j], wuj = wupa[j];
        a0[0]=fmaf(w0j,h0a.x,a0[0]); a0[1]=fmaf(w0j,h0a.y,a0[1]);
        a0[2]=fmaf(w0j,h0a.z,a0[2]); a0[3]=fmaf(w0j,h0a.w,a0[3]);
        a0[4]=fmaf(w0j,h0b.x,a0[4]); a0[5]=fmaf(w0j,h0b.y,a0[5]);
        a0[6]=fmaf(w0j,h0b.z,a0[6]); a0[7]=fmaf(w0j,h0b.w,a0[7]);
        a1[0]=fmaf(wlj,h0a.x,a1[0]); a1[1]=fmaf(wlj,h0a.y,a1[1]);
        a1[2]=fmaf(wlj,h0a.z,a1[2]); a1[3]=fmaf(wlj,h0a.w,a1[3]);
        a1[4]=fmaf(wlj,h0b.x,a1[4]); a1[5]=fmaf(wlj,h0b.y,a1[5]);
        a1[6]=fmaf(wlj,h0b.z,a1[6]); a1[7]=fmaf(wlj,h0b.w,a1[7]);
        a1[0]=fmaf(wuj,h1a.x,a1[0]); a1[1]=fmaf(wuj,h1a.y,a1[1]);
        a1[2]=fmaf(wuj,h1a.z,a1[2]); a1[3]=fmaf(wuj,h1a.w,a1[3]);
        a1[4]=fmaf(wuj,h1b.x,a1[4]); a1[5]=fmaf(wuj,h1b.y,a1[5]);
        a1[6]=fmaf(wuj,h1b.z,a1[6]); a1[7]=fmaf(wuj,h1b.w,a1[7]);
      }
    }

    // ---- projection partial over this wave's k-quarter (h1s = H1(t-1)) ----
    float pacc = 0.f;
    {
      const int kq = wv*64;
      #pragma unroll 4
      for (int k2 = 0; k2 < 64; k2 += 4) {
        const f4 w4 = *(const f4*)&ldsW[pv][kq + k2];
        pacc = fmaf(h1s[kq+k2  ][pm], w4.x, pacc);
        pacc = fmaf(h1s[kq+k2+1][pm], w4.y, pacc);
        pacc = fmaf(h1s[kq+k2+2][pm], w4.z, pacc);
        pacc = fmaf(h1s[kq+k2+3][pm], w4.w, pacc);
      }
    }

    #pragma unroll
    for (int r = 0; r < 8; ++r) { za[wv][r][lane] = a0[r]; zb[wv][r][lane] = a1[r]; }
    pred[wv][lane] = pacc;
    __syncthreads();                                   // (3)

    if (wv == 0) {
      // gates L0 -> H0(t+1), publish to buf^1
      if (t + 1 < Lg) {
        f4 sA = *(const f4*)&za[0][q][gu*4];
        sA += *(const f4*)&za[1][q][gu*4];
        sA += *(const f4*)&za[2][q][gu*4];
        sA += *(const f4*)&za[3][q][gu*4];
        f4 sB = *(const f4*)&za[0][q+4][gu*4];
        sB += *(const f4*)&za[1][q+4][gu*4];
        sB += *(const f4*)&za[2][q+4][gu*4];
        sB += *(const f4*)&za[3][q+4][gu*4];
        f4 zA = sA + tpA + cpA;
        f4 zB = sB + tpB + cpB;
        lstm_gate(zA, c0A, h0A, (t+1) < lenA);
        lstm_gate(zB, c0B, h0B, (t+1) < lenB);
        float* pb = ht0 + (buf^1)*GST + puboff;
        st_coh(pb + q,     h0A);
        st_coh(pb + q + 4, h0B);
        if (lane == 0) flag_set(fA + c, (unsigned)(t + 2));
      }
    } else if (wv == 1) {
      // gates L1 -> H1(t), publish to buf^1
      f4 sA = *(const f4*)&zb[0][q][gu*4];
      sA += *(const f4*)&zb[1][q][gu*4];
      sA += *(const f4*)&zb[2][q][gu*4];
      sA += *(const f4*)&zb[3][q][gu*4];
      f4 sB = *(const f4*)&zb[0][q+4][gu*4];
      sB += *(const f4*)&zb[1][q+4][gu*4];
      sB += *(const f4*)&zb[2][q+4][gu*4];
      sB += *(const f4*)&zb[3][q+4][gu*4];
      f4 zA = sA + b1v;
      f4 zB = sB + b1v;
      lstm_gate(zA, c1A, h1A, t < lenA);
      lstm_gate(zB, c1B, h1B, t < lenB);
      float* pb = ht1 + (buf^1)*GST + puboff;
      st_coh(pb + q,     h1A);
      st_coh(pb + q + 4, h1B);
      if (lane == 0) flag_set(fB + c, (unsigned)(t + 2));
    } else if (wv == 2) {
      // out(t-1) from this iteration's pred (computed from H1(t-1))
      if (t > 0) {
        float tot = pred[0][lane] + pred[1][lane] + pred[2][lane] + pred[3][lane] + decb;
        if (t - 1 < plen) outp[(size_t)(t-1)*V_] = tot;
      }
    }
  }

  // ---- epilogue: out(Lg-1) from H1(Lg-1) in buf (Lg&1), fB reaches Lg+1 ----
  if (wv == 0) spin1(fB, lane, (unsigned)(Lg + 1));
  __syncthreads();
  __atomic_signal_fence(__ATOMIC_SEQ_CST);
  stage_row(ht1 + (Lg & 1)*GST + grp*HTG + sk*8, &h1s[sk][0]);
  __syncthreads();
  {
    float pacc = 0.f;
    const int kq = wv*64;
    #pragma unroll 4
    for (int k2 = 0; k2 < 64; k2 += 4) {
      const f4 w4 = *(const f4*)&ldsW[pv][kq + k2];
      pacc = fmaf(h1s[kq+k2  ][pm], w4.x, pacc);
      pacc = fmaf(h1s[kq+k2+1][pm], w4.y, pacc);
      pacc = fmaf(h1s[kq+k2+2][pm], w4.z, pacc);
      pacc = fmaf(h1s[kq+k2+3][pm], w4.w, pacc);
    }
    pred[wv][lane] = pacc;
  }
  __syncthreads();
  if (wv == 2) {
    float tot = pred[0][lane] + pred[1][lane] + pred[2][lane] + pred[3][lane] + decb;
    if (Lg - 1 < plen) outp[(size_t)(Lg-1)*V_] = tot;
  }
}

// ============ launch ============

extern "C" void kernel_launch(void* const* d_in, const int* in_sizes, int n_in,
                              void* d_out, int out_size, void* d_ws, size_t ws_size,
                              hipStream_t stream) {
  const int*   toks  = (const int*)d_in[0];
  const int*   lens  = (const int*)d_in[1];
  const int*   clus  = (const int*)d_in[2];
  const float* cemb  = (const float*)d_in[3];
  const float* clemb = (const float*)d_in[4];
  const float* W0    = (const float*)d_in[5];
  const float* b0    = (const float*)d_in[6];
  const float* W1    = (const float*)d_in[7];
  const float* b1    = (const float*)d_in[8];
  const float* dW    = (const float*)d_in[9];
  const float* decB  = (const float*)d_in[10];
  float* out = (float*)d_out;
  float* ws  = (float*)d_ws;

  // zero output (masked positions must be exactly 0), h buffers (H1(-1)=0),
  // and the flag block
  hipMemsetAsync(out, 0, (size_t)B_*T_*V_*sizeof(float), stream);
  hipMemsetAsync(ws, 0, (size_t)(OFF_BAR + 4096)*sizeof(float), stream);

  prep_pack<<<1024, 256, 0, stream>>>(W0, W1, dW, b1, ws);
  prep_tok <<<V_*4, 256, 0, stream>>>(cemb, W0, ws);
  prep_clus<<<B_*4, 256, 0, stream>>>(clus, clemb, W0, b0, ws);
  lstm_persist<<<NWG, 256, 0, stream>>>(toks, lens, decB, ws, out);
}